// Round 12
// baseline (172.396 us; speedup 1.0000x reference)
//
#include <hip/hip_runtime.h>

// SSIM (skimage default): 7x7 uniform filter, valid crop (pad=3), sample cov.
// Images: 4096x4096 fp32, output region 4090x4090, result = mean(S) scalar.
//
// R12: full-strip LDS staging. Diagnosis across R0-R11: inner-loop global
// loads hit L3 (~500-700cy; inputs are L3-resident, FETCH < compulsory 128MB
// proves it) and the ring's ~150-reg unified footprint caps occupancy at
// 2-3 waves/SIMD -- too few to hide L3 latency (need ~4+). All schedule-level
// fixes failed (R6/R7/R8: reorder attempts; R11: work amortization lost more
// occupancy than it saved). Fix the LATENCY CLASS instead: bulk-stage the
// block's whole input tile (2 img x 14 rows x 518 cols = 58KB) to LDS once
// (one exposed global-latency event per strip, coalesced float4s), then the
// unchanged R9 ring loop reads float2s from LDS (ds_read ~120cy -- hideable
// by 2 waves/SIMD against ~210cy/row of VALU).
//  - ROWS=8 (LDS 58.2KB < 64KB static cap); grid 8x512; rows_in guards the
//    2-row tail strip. Ring/guard skeleton byte-identical to R9 (rules
//    R1-R8 still honored). Bank check: lane i at 8i-byte offsets = 2-way = free.
//  - stage addressing is shift/mask only (128 f4-cols bulk + 6-col halo).
//  - epilogue algebra (R8/R9) + single-kernel atomic (R10) kept.
// History: R0 92 -> R4 74.5 -> R9/R10 72 (VALU 33, stall 39) -> R11 95
// (4px/thr: VALU 24 but stall 71 at 2 waves/SIMD).
// Falsifier: ssim_main > 72us -> LDS loses to L3-direct; revert to R9.

#define W_IMG   4096
#define H_IMG   4096
#define OW      4090
#define OH      4090
#define ROWS    8             // output rows per block strip (tail guarded)
#define IN_ROWS (ROWS + 6)    // 14 input rows staged
#define NTHR    256           // threads per block
#define CPB     512           // output columns per block (2 per thread)
#define LDS_W   520           // row stride in floats (518 used + pad)

// generic-pointer hsums: works on LDS-derived pointers (emits ds_read_b64)
__device__ __forceinline__ void hsums(const float* pO, const float* pT,
                                      float h[10])
{
    float2 a0 = *(const float2*)(pO + 0);
    float2 a1 = *(const float2*)(pO + 2);
    float2 a2 = *(const float2*)(pO + 4);
    float2 a3 = *(const float2*)(pO + 6);
    float2 b0 = *(const float2*)(pT + 0);
    float2 b1 = *(const float2*)(pT + 2);
    float2 b2 = *(const float2*)(pT + 4);
    float2 b3 = *(const float2*)(pT + 6);
    float o0=a0.x,o1=a0.y,o2=a1.x,o3=a1.y,o4=a2.x,o5=a2.y,o6=a3.x,o7=a3.y;
    float t0=b0.x,t1=b0.y,t2=b1.x,t3=b1.y,t4=b2.x,t5=b2.y,t6=b3.x,t7=b3.y;

    float so  = ((o0+o1)+(o2+o3)) + ((o4+o5)+o6);
    float st  = ((t0+t1)+(t2+t3)) + ((t4+t5)+t6);
    float soo = fmaf(o6,o6, fmaf(o5,o5, fmaf(o4,o4, fmaf(o3,o3, fmaf(o2,o2, fmaf(o1,o1, o0*o0))))));
    float stt = fmaf(t6,t6, fmaf(t5,t5, fmaf(t4,t4, fmaf(t3,t3, fmaf(t2,t2, fmaf(t1,t1, t0*t0))))));
    float sot = fmaf(o6,t6, fmaf(o5,t5, fmaf(o4,t4, fmaf(o3,t3, fmaf(o2,t2, fmaf(o1,t1, o0*t0))))));

    h[0] = so;   h[1] = so  - o0    + o7;
    h[2] = st;   h[3] = st  - t0    + t7;
    h[4] = soo;  h[5] = soo - o0*o0 + o7*o7;
    h[6] = stt;  h[7] = stt - t0*t0 + t7*t7;
    h[8] = sot;  h[9] = sot - o0*t0 + o7*t7;
}

// Scaled SSIM num/den (R8/R9 verified): A1,B1 *= 49^2; A2,B2 *= 48*49.
__device__ __forceinline__ void ssim_nd(const float v[10], int px,
                                        float& num, float& den)
{
    const float K1 = 0.9604f;     // 4.0e-4 * 2401
    const float K2 = 8.4672f;     // 3.6e-3 * 2352
    float so  = v[0+px], st  = v[2+px];
    float soo = v[4+px], stt = v[6+px], sot = v[8+px];
    float t1 = so*st;
    float A1 = fmaf(2.0f, t1, K1);
    float ss = fmaf(st, st, so*so);
    float B1 = ss + K1;
    float A2 = fmaf(98.0f, sot, fmaf(-2.0f, t1, K2));
    float B2 = fmaf(49.0f, soo + stt, K2 - ss);
    num = A1*A2;
    den = B1*B2;
}

__global__ __launch_bounds__(NTHR, 3)
void ssim_main(const float* __restrict__ O, const float* __restrict__ T,
               float* __restrict__ outp)
{
    __shared__ float lds[2][IN_ROWS][LDS_W];   // 58,240 B
    __shared__ float wpart[NTHR / 64];

    const int t   = threadIdx.x;
    const int bxc = blockIdx.x * CPB;          // block's input-col base
    const int r0  = blockIdx.y * ROWS;         // first output row of strip
    const int rows_in = min(ROWS, OH - r0);    // runtime (2 on tail strip)

    // ---- stage: 2 images x 14 rows x 518 cols -> LDS (coalesced) ----
    {
        const int hi = t >> 7;                 // 0/1: row half
        const int cg = t & 127;                // float4 column 0..127
        const float* img[2] = { O, T };
        #pragma unroll
        for (int m = 0; m < 2; m++) {
            const float* base = img[m];
            #pragma unroll
            for (int k = 0; k < 7; k++) {
                const int row = 2*k + hi;                       // 0..13
                const int gr  = min(r0 + row, H_IMG - 1);       // tail clamp
                float4 val = *(const float4*)(base + (size_t)gr * W_IMG
                                              + bxc + 4*cg);    // cols 0..511
                *(float4*)&lds[m][row][4*cg] = val;
            }
        }
        // halo cols 512..517 (6 floats per row per image)
        if (t < 2 * IN_ROWS * 8) {             // 224 threads
            const int m    = t >= IN_ROWS * 8; // image select
            const int tt   = t - m * IN_ROWS * 8;
            const int row  = tt >> 3;          // 0..13
            const int part = tt & 7;
            if (part < 3) {
                const int gr = min(r0 + row, H_IMG - 1);
                const int gc = min(bxc + 512 + 2*part, W_IMG - 2); // even
                float2 vv = *(const float2*)(img[m] + (size_t)gr * W_IMG + gc);
                *(float2*)&lds[m][row][512 + 2*part] = vv;
            }
        }
    }
    __syncthreads();

    // ---- compute: R9's ring loop, pointers into LDS ----
    const int c0 = bxc + 2*t;                  // first of the 2 output cols
    float acc = 0.0f;

    if (c0 < OW) {  // c0 even, OW even -> both pixels valid together
        const float* baseO = &lds[0][0][2*t];
        const float* baseT = &lds[1][0][2*t];

        float ring[7][10];   // 7-row delay line of horizontal sums (AGPRs)
        float v[10];         // running vertical sums over the 7-row window
        #pragma unroll
        for (int q = 0; q < 10; q++) v[q] = 0.0f;

        // warm-up: input rows 0..5
        #pragma unroll
        for (int i = 0; i < 6; i++) {
            float h[10];
            hsums(baseO + i * LDS_W, baseT + i * LDS_W, h);
            #pragma unroll
            for (int q = 0; q < 10; q++) { v[q] += h[q]; ring[i][q] = h[q]; }
        }

        // steady: output row j (input row i = j+6); chunked by 7 so ring
        // slot indices are compile-time constants (stays in VGPRs/AGPRs).
        for (int jb = 0; jb < ROWS; jb += 7) {
            #pragma unroll
            for (int u = 0; u < 7; u++) {
                const int j = jb + u;
                if (j < rows_in) {
                    const int i = j + 6;
                    float h[10];
                    hsums(baseO + i * LDS_W, baseT + i * LDS_W, h);
                    #pragma unroll
                    for (int q = 0; q < 10; q++) v[q] += h[q];
                    // window now covers rows [j, j+6]
                    float n0, d0, n1, d1;
                    ssim_nd(v, 0, n0, d0);
                    ssim_nd(v, 1, n1, d1);
                    acc = fmaf(fmaf(n0, d1, n1*d0),
                               __builtin_amdgcn_rcpf(d0*d1), acc);
                    // drop row i-6 (slot u), store row i (slot (u+6)%7)
                    #pragma unroll
                    for (int q = 0; q < 10; q++) {
                        v[q] -= ring[u][q];
                        ring[(u + 6) % 7][q] = h[q];
                    }
                }
            }
        }
    }

    // wave(64) shuffle reduction
    #pragma unroll
    for (int off = 32; off; off >>= 1) acc += __shfl_down(acc, off);

    if ((t & 63) == 0) wpart[t >> 6] = acc;
    __syncthreads();
    if (t == 0) {
        float s = 0.0f;
        #pragma unroll
        for (int w = 0; w < NTHR / 64; w++) s += wpart[w];
        const float inv = (float)(1.0 / ((double)OW * (double)OH));
        atomicAdd(outp, s * inv);   // pre-scaled, straight into d_out
    }
}

extern "C" void kernel_launch(void* const* d_in, const int* in_sizes, int n_in,
                              void* d_out, int out_size, void* d_ws, size_t ws_size,
                              hipStream_t stream)
{
    const float* O = (const float*)d_in[0];
    const float* T = (const float*)d_in[1];
    float* out = (float*)d_out;

    hipMemsetAsync(out, 0, sizeof(float), stream);   // accumulate in d_out

    dim3 grid((OW + CPB - 1) / CPB, (OH + ROWS - 1) / ROWS);  // (8, 512)
    ssim_main<<<grid, NTHR, 0, stream>>>(O, T, out);
}